// Round 7
// baseline (483.886 us; speedup 1.0000x reference)
//
#include <hip/hip_runtime.h>

// VectorQuantizer: inputs [65536,128] f32, codebook [1024,128] f32.
// Outputs flat f32: loss(1) | quantized_st(65536*128) | perplexity(1) | encodings(65536*1024)
#define NROWS 65536
#define DIM   128
#define KC    1024
#define QST_OFF  1
#define PPL_OFF  8388609
#define ENC_OFF  8388610

typedef float f32x2 __attribute__((ext_vector_type(2)));
typedef float floatx4 __attribute__((ext_vector_type(4)));
typedef _Float16 half8_t __attribute__((ext_vector_type(8)));
typedef _Float16 half4_t __attribute__((ext_vector_type(4)));

#define BSTR 144                  // row stride in halfs (288 B)
#define ALO  9216                 // A-image lo offset (64*144)
#define CH32 9216                 // halfs per 32-code chunk (hi 32*144 + lo 32*144)
#define BLO  4608                 // lo offset within a chunk (32*144)
#define NCH  32                   // chunks of 32 codes

// --- rounding-exact helpers: numpy-replica fp32 elementwise ops, no contraction ---
__device__ __forceinline__ float fadd_rn_(float a, float b) {
#pragma clang fp contract(off)
  return a + b;
}
__device__ __forceinline__ float fsub_rn_(float a, float b) {
#pragma clang fp contract(off)
  return a - b;
}
__device__ __forceinline__ float fmul_rn_(float a, float b) {
#pragma clang fp contract(off)
  return a * b;
}

// numpy pairwise_sum(x*x) for n=128: 8 accumulators, strided, fixed combine tree.
__device__ __forceinline__ float rowsq128(const float4* src) {
  float r[8];
  {
    float4 v0 = src[0], v1 = src[1];
    r[0] = fmul_rn_(v0.x, v0.x); r[1] = fmul_rn_(v0.y, v0.y);
    r[2] = fmul_rn_(v0.z, v0.z); r[3] = fmul_rn_(v0.w, v0.w);
    r[4] = fmul_rn_(v1.x, v1.x); r[5] = fmul_rn_(v1.y, v1.y);
    r[6] = fmul_rn_(v1.z, v1.z); r[7] = fmul_rn_(v1.w, v1.w);
  }
  for (int i = 1; i < 16; ++i) {
    float4 v0 = src[2 * i], v1 = src[2 * i + 1];
    r[0] = fadd_rn_(r[0], fmul_rn_(v0.x, v0.x));
    r[1] = fadd_rn_(r[1], fmul_rn_(v0.y, v0.y));
    r[2] = fadd_rn_(r[2], fmul_rn_(v0.z, v0.z));
    r[3] = fadd_rn_(r[3], fmul_rn_(v0.w, v0.w));
    r[4] = fadd_rn_(r[4], fmul_rn_(v1.x, v1.x));
    r[5] = fadd_rn_(r[5], fmul_rn_(v1.y, v1.y));
    r[6] = fadd_rn_(r[6], fmul_rn_(v1.z, v1.z));
    r[7] = fadd_rn_(r[7], fmul_rn_(v1.w, v1.w));
  }
  return fadd_rn_(fadd_rn_(fadd_rn_(r[0], r[1]), fadd_rn_(r[2], r[3])),
                  fadd_rn_(fadd_rn_(r[4], r[5]), fadd_rn_(r[6], r[7])));
}

// K_prep (16 blocks x 64 codes): cbT transpose, exact cc chain, fp16 hi/lo pack
// into 32-code chunks [hi 32x144 | lo 32x144].
__global__ __launch_bounds__(256) void k_prep(const float* __restrict__ cb,
                                              float* __restrict__ cbT,
                                              float* __restrict__ cc,
                                              _Float16* __restrict__ Bp) {
  __shared__ float tile[64 * 129];  // +1 pad: conflict-free transpose
  int t = threadIdx.x;
  int c0 = blockIdx.x * 64;
#pragma unroll
  for (int it = 0; it < 32; ++it) {
    int f = it * 256 + t;
    int c = f >> 7, d = f & 127;
    tile[c * 129 + d] = cb[(size_t)(c0 + c) * DIM + d];
  }
  __syncthreads();
#pragma unroll
  for (int it = 0; it < 32; ++it) {
    int f = it * 256 + t;
    int d = f >> 6, c = f & 63;
    cbT[(size_t)d * KC + c0 + c] = tile[c * 129 + d];
  }
  if (t < 64) {
    const float* s = &tile[t * 129];
    float r[8];
#pragma unroll
    for (int j = 0; j < 8; ++j) r[j] = fmul_rn_(s[j], s[j]);
    for (int i = 1; i < 16; ++i) {
#pragma unroll
      for (int j = 0; j < 8; ++j)
        r[j] = fadd_rn_(r[j], fmul_rn_(s[i * 8 + j], s[i * 8 + j]));
    }
    cc[c0 + t] = fadd_rn_(fadd_rn_(fadd_rn_(r[0], r[1]), fadd_rn_(r[2], r[3])),
                          fadd_rn_(fadd_rn_(r[4], r[5]), fadd_rn_(r[6], r[7])));
  }
#pragma unroll
  for (int it = 0; it < 32; ++it) {
    int f = it * 256 + t;
    int c = f >> 7, k = f & 127;       // c: 0..63 local code
    int gc = c0 + c;
    int chunk = gc >> 5, cr = gc & 31;
    float c5 = tile[c * 129 + k] * 512.0f;  // exact pow2 scale
    _Float16 h = (_Float16)c5;
    _Float16 l = (_Float16)(c5 - (float)h);
    size_t base = (size_t)chunk * CH32;
    Bp[base + cr * BSTR + k] = h;
    Bp[base + BLO + cr * BSTR + k] = l;
  }
}

// K_main: 64 rows/block, 256 thr (4 waves x 16 rows). fp16-split MFMA distance
// GEMM with PING-PONG B buffers (32 chunks x 32 codes; loads for c+1 in flight
// during MFMA of c; one barrier per chunk) + margin argmin + inline exact
// recheck + fused epilogue.
__global__ __launch_bounds__(256, 4) void k_main(const float* __restrict__ inp,
                                                 const float* __restrict__ cb,
                                                 const float* __restrict__ cbT,
                                                 const _Float16* __restrict__ Bp,
                                                 const float* __restrict__ cc,
                                                 float* __restrict__ out_qst,
                                                 float* __restrict__ out_enc,
                                                 int* __restrict__ cnt,
                                                 float* __restrict__ lsum) {
  __shared__ _Float16 SB[2 * CH32];  // 36864 B: A-split image, then B ping-pong
  __shared__ float xxs[64];
  __shared__ int bk[64];
  __shared__ int fl_rows[64];
  __shared__ int fl_cnt;
  __shared__ float xs[128];
  __shared__ float redd[4];
  __shared__ int redi[4];
  __shared__ float redf[4];

  int t = threadIdx.x;
  int lane = t & 63, w = t >> 6;
  int q = lane >> 4, col = lane & 15;
  int row0 = blockIdx.x * 64;
  if (t == 0) fl_cnt = 0;

  // ---- stage A as fp16 hi/lo split (occupies BOTH B buffers temporarily) ----
  {
    int r = t & 63, seg = t >> 6;
    const float* src = inp + (size_t)(row0 + r) * DIM + seg * 32;
#pragma unroll
    for (int i = 0; i < 8; ++i) {
      float4 v = *(const float4*)(src + i * 4);
      _Float16 h0 = (_Float16)v.x, h1 = (_Float16)v.y, h2 = (_Float16)v.z, h3 = (_Float16)v.w;
      half4_t hv = {h0, h1, h2, h3};
      half4_t lv = {(_Float16)(v.x - (float)h0), (_Float16)(v.y - (float)h1),
                    (_Float16)(v.z - (float)h2), (_Float16)(v.w - (float)h3)};
      int k = seg * 32 + i * 4;
      *(half4_t*)&SB[r * BSTR + k] = hv;
      *(half4_t*)&SB[ALO + r * BSTR + k] = lv;
    }
  }
  if (t < 64) xxs[t] = rowsq128((const float4*)(inp + (size_t)(row0 + t) * DIM));
  __syncthreads();

  // ---- A frags -> registers ----
  int arow = w * 16 + col;
  half8_t ah[4], al[4];
#pragma unroll
  for (int ks = 0; ks < 4; ++ks) {
    ah[ks] = *(const half8_t*)&SB[arow * BSTR + ks * 32 + q * 8];
    al[ks] = *(const half8_t*)&SB[ALO + arow * BSTR + ks * 32 + q * 8];
  }
  float xr[4];
#pragma unroll
  for (int r = 0; r < 4; ++r) xr[r] = xxs[w * 16 + q * 4 + r];

  float b1[4], b2[4];
  int i1[4];
#pragma unroll
  for (int r = 0; r < 4; ++r) { b1[r] = 3.4e38f; b2[r] = 3.4e38f; i1[r] = 0; }

  const float4* bp4 = (const float4*)Bp;   // chunk stride = 1152 float4
  float4* SBf4 = (float4*)SB;              // buffer stride = 1152 float4

  // preload chunk 0 into regs while A-frag extraction finishes
  float4 br[5];
#pragma unroll
  for (int r = 0; r < 4; ++r) br[r] = bp4[r * 256 + t];
  if (t < 128) br[4] = bp4[1024 + t];

  __syncthreads();  // all waves done reading the A image from SB

  // publish chunk 0 into buf0
#pragma unroll
  for (int r = 0; r < 4; ++r) SBf4[r * 256 + t] = br[r];
  if (t < 128) SBf4[1024 + t] = br[4];
  __syncthreads();

  for (int c = 0; c < NCH; ++c) {
    const _Float16* cur = &SB[(c & 1) * CH32];

    // issue loads for chunk c+1 (in flight across the MFMA section)
    if (c < NCH - 1) {
#pragma unroll
      for (int r = 0; r < 4; ++r) br[r] = bp4[(c + 1) * 1152 + r * 256 + t];
      if (t < 128) br[4] = bp4[(c + 1) * 1152 + 1024 + t];
    }

    float cck[2];
#pragma unroll
    for (int ct = 0; ct < 2; ++ct) cck[ct] = cc[c * 32 + ct * 16 + col];

    floatx4 acc[2];
#pragma unroll
    for (int ct = 0; ct < 2; ++ct) acc[ct] = (floatx4){0.f, 0.f, 0.f, 0.f};

#pragma unroll
    for (int ks = 0; ks < 4; ++ks) {
#pragma unroll
      for (int ct = 0; ct < 2; ++ct) {
        int brow = ct * 16 + col;
        half8_t bh = *(const half8_t*)&cur[brow * BSTR + ks * 32 + q * 8];
        half8_t bl = *(const half8_t*)&cur[BLO + brow * BSTR + ks * 32 + q * 8];
        acc[ct] = __builtin_amdgcn_mfma_f32_16x16x32_f16(ah[ks], bh, acc[ct], 0, 0, 0);
        acc[ct] = __builtin_amdgcn_mfma_f32_16x16x32_f16(ah[ks], bl, acc[ct], 0, 0, 0);
        acc[ct] = __builtin_amdgcn_mfma_f32_16x16x32_f16(al[ks], bh, acc[ct], 0, 0, 0);
      }
    }

#pragma unroll
    for (int ct = 0; ct < 2; ++ct) {
#pragma unroll
      for (int r = 0; r < 4; ++r) {
        float m2 = fmul_rn_(acc[ct][r], 0.00390625f);  // fl(2*matmul), exact unscale
        float dist = fsub_rn_(fadd_rn_(xr[r], cck[ct]), m2);
        int kidx = c * 32 + ct * 16 + col;
        bool lt = dist < b1[r];
        b2[r] = lt ? b1[r] : fminf(b2[r], dist);
        i1[r] = lt ? kidx : i1[r];
        b1[r] = lt ? dist : b1[r];
      }
    }

    // publish chunk c+1 into the other buffer (safe: that buffer's readers
    // finished before the barrier that admitted us into iter c)
    if (c < NCH - 1) {
      float4* dst = &SBf4[((c + 1) & 1) * 1152];
#pragma unroll
      for (int r = 0; r < 4; ++r) dst[r * 256 + t] = br[r];
      if (t < 128) dst[1024 + t] = br[4];
    }
    __syncthreads();
  }

  // top-2 reduce across the 16 col-lanes; tie -> lower index
#pragma unroll
  for (int r = 0; r < 4; ++r) {
    float v1 = b1[r], v2 = b2[r];
    int ii = i1[r];
    for (int off = 1; off < 16; off <<= 1) {
      float ov1 = __shfl_xor(v1, off);
      float ov2 = __shfl_xor(v2, off);
      int oi = __shfl_xor(ii, off);
      float nb1 = fminf(v1, ov1);
      float nb2 = fminf(fmaxf(v1, ov1), fminf(v2, ov2));
      ii = (ov1 < v1) ? oi : ((ov1 > v1) ? ii : min(ii, oi));
      v1 = nb1; v2 = nb2;
    }
    b1[r] = v1; b2[r] = v2; i1[r] = ii;
  }

  if (col == 0) {
#pragma unroll
    for (int r = 0; r < 4; ++r) {
      int lrow = w * 16 + q * 4 + r;
      bk[lrow] = i1[r];
      float u = (b1[r] >= 256.f) ? 9.4e-5f : 4.7e-5f;  // 3-ulp tiered margin
      if (b2[r] - b1[r] < u) {
        int p = atomicAdd(&fl_cnt, 1);
        fl_rows[p] = lrow;
      }
    }
  }
  __syncthreads();

  // ---- inline exact fp32 recheck of flagged rows (rare) ----
  int nf = fl_cnt;
  for (int f = 0; f < nf; ++f) {
    int row = fl_rows[f];
    if (t < 128) xs[t] = inp[(size_t)(row0 + row) * DIM + t];
    __syncthreads();
    float xxr = xxs[row];
    int c0 = t * 4;
    float a0 = 0.f, a1 = 0.f, a2 = 0.f, a3 = 0.f;
    for (int d = 0; d < 128; ++d) {
      float xd = xs[d];
      float4 cv = *(const float4*)&cbT[(size_t)d * KC + c0];
      a0 = __builtin_fmaf(xd, cv.x, a0);
      a1 = __builtin_fmaf(xd, cv.y, a1);
      a2 = __builtin_fmaf(xd, cv.z, a2);
      a3 = __builtin_fmaf(xd, cv.w, a3);
    }
    float aa[4] = {a0, a1, a2, a3};
    float bb = 3.4e38f;
    int bi = 0;
#pragma unroll
    for (int j = 0; j < 4; ++j) {
      float dist = fsub_rn_(fadd_rn_(xxr, cc[c0 + j]), fmul_rn_(2.0f, aa[j]));
      if (dist < bb) { bb = dist; bi = c0 + j; }
    }
    for (int off = 1; off < 64; off <<= 1) {
      float ov = __shfl_xor(bb, off);
      int oi = __shfl_xor(bi, off);
      if (ov < bb || (ov == bb && oi < bi)) { bb = ov; bi = oi; }
    }
    if (lane == 0) { redd[w] = bb; redi[w] = bi; }
    __syncthreads();
    if (t == 0) {
      float vb = redd[0];
      int ib = redi[0];
#pragma unroll
      for (int ww = 1; ww < 4; ++ww) {
        if (redd[ww] < vb || (redd[ww] == vb && redi[ww] < ib)) { vb = redd[ww]; ib = redi[ww]; }
      }
      bk[row] = ib;
    }
    __syncthreads();
  }

  // ---- epilogue (R1-proven write patterns) ----
  if (t < 64) atomicAdd(&cnt[bk[t]], 1);

  float ls = 0.f;
#pragma unroll 4
  for (int it = 0; it < 32; ++it) {
    int f = it * 256 + t;  // 64 rows x 128 d, linear
    int row = f >> 7, d = f & 127;
    size_t gro = (size_t)(row0 + row) * DIM + d;
    float x = inp[gro];
    float qv = cb[(size_t)bk[row] * DIM + d];
    float qe = fsub_rn_(qv, x);
    out_qst[gro] = fadd_rn_(x, qe);  // == np: inputs + (quantized - inputs)
    ls = __builtin_fmaf(qe, qe, ls);
  }

  for (int it = 0; it < 128; ++it) {
    int f2 = it * 256 + t;  // 64 rows x 512 f32x2
    int row = f2 >> 9, c2 = f2 & 511;
    int kk = bk[row];
    f32x2 v;
    v.x = (kk == 2 * c2) ? 1.0f : 0.0f;
    v.y = (kk == 2 * c2 + 1) ? 1.0f : 0.0f;
    *(f32x2*)&out_enc[(size_t)(row0 + row) * KC + 2 * c2] = v;
  }

  for (int off = 32; off; off >>= 1) ls += __shfl_down(ls, off);
  if (lane == 0) redf[w] = ls;
  __syncthreads();
  if (t == 0) atomicAdd(lsum, redf[0] + redf[1] + redf[2] + redf[3]);
}

// K_scalars: loss + perplexity
__global__ __launch_bounds__(1024) void k_scalars(const int* __restrict__ cnt,
                                                  const float* __restrict__ lsum,
                                                  float* __restrict__ out) {
  int t = threadIdx.x;
  float p = (float)cnt[t] * (1.0f / 65536.0f);
  float term = fmul_rn_(p, logf(fadd_rn_(p, 1e-10f)));
  for (int off = 32; off; off >>= 1) term += __shfl_down(term, off);
  __shared__ float red[16];
  if ((t & 63) == 0) red[t >> 6] = term;
  __syncthreads();
  if (t == 0) {
    float s = 0.f;
#pragma unroll
    for (int w = 0; w < 16; ++w) s += red[w];
    out[PPL_OFF] = expf(-s);
    float e = *lsum * (1.0f / 8388608.0f);
    out[0] = fadd_rn_(e, fmul_rn_(0.25f, e));  // q_latent + 0.25*e_latent (equal)
  }
}

extern "C" void kernel_launch(void* const* d_in, const int* in_sizes, int n_in,
                              void* d_out, int out_size, void* d_ws, size_t ws_size,
                              hipStream_t stream) {
  const float* inp = (const float*)d_in[0];
  const float* cb = (const float*)d_in[1];
  float* out = (float*)d_out;

  _Float16* Bp = (_Float16*)d_ws;          // 32*9216 halfs = 589824 B
  float* cbT = (float*)(Bp + 32 * CH32);   // 131072 f32
  float* cc = cbT + DIM * KC;              // 1024 f32
  int* cnt = (int*)(cc + KC);              // 1024 i32
  float* lsum = (float*)(cnt + KC);        // 1 f32

  (void)hipMemsetAsync(cnt, 0, (KC + 1) * sizeof(int), stream);
  k_prep<<<KC / 64, 256, 0, stream>>>(cb, cbT, cc, Bp);
  k_main<<<NROWS / 64, 256, 0, stream>>>(inp, cb, cbT, Bp, cc,
                                         out + QST_OFF, out + ENC_OFF, cnt, lsum);
  k_scalars<<<1, 1024, 0, stream>>>(cnt, lsum, out);
}

// Round 8
// 418.130 us; speedup vs baseline: 1.1573x; 1.1573x over previous
//
#include <hip/hip_runtime.h>

// VectorQuantizer: inputs [65536,128] f32, codebook [1024,128] f32.
// Outputs flat f32: loss(1) | quantized_st(65536*128) | perplexity(1) | encodings(65536*1024)
#define NROWS 65536
#define DIM   128
#define KC    1024
#define QST_OFF  1
#define PPL_OFF  8388609
#define ENC_OFF  8388610

typedef float f32x2 __attribute__((ext_vector_type(2)));
typedef float floatx4 __attribute__((ext_vector_type(4)));
typedef _Float16 half8_t __attribute__((ext_vector_type(8)));
typedef _Float16 half4_t __attribute__((ext_vector_type(4)));

#define BSTR 144                  // row stride in halfs (288 B)
#define ALO  9216                 // A-image lo offset (64*144 halfs)
#define CH32 9216                 // halfs per 32-code chunk (hi 32*144 + lo 32*144)
#define CHB  18432                // bytes per chunk
#define BLO  4608                 // lo offset within a chunk (halfs)
#define NCH  32                   // chunks of 32 codes

// --- rounding-exact helpers: numpy-replica fp32 elementwise ops, no contraction ---
__device__ __forceinline__ float fadd_rn_(float a, float b) {
#pragma clang fp contract(off)
  return a + b;
}
__device__ __forceinline__ float fsub_rn_(float a, float b) {
#pragma clang fp contract(off)
  return a - b;
}
__device__ __forceinline__ float fmul_rn_(float a, float b) {
#pragma clang fp contract(off)
  return a * b;
}

// numpy pairwise_sum(x*x) for n=128: 8 accumulators, strided, fixed combine tree.
__device__ __forceinline__ float rowsq128(const float4* src) {
  float r[8];
  {
    float4 v0 = src[0], v1 = src[1];
    r[0] = fmul_rn_(v0.x, v0.x); r[1] = fmul_rn_(v0.y, v0.y);
    r[2] = fmul_rn_(v0.z, v0.z); r[3] = fmul_rn_(v0.w, v0.w);
    r[4] = fmul_rn_(v1.x, v1.x); r[5] = fmul_rn_(v1.y, v1.y);
    r[6] = fmul_rn_(v1.z, v1.z); r[7] = fmul_rn_(v1.w, v1.w);
  }
  for (int i = 1; i < 16; ++i) {
    float4 v0 = src[2 * i], v1 = src[2 * i + 1];
    r[0] = fadd_rn_(r[0], fmul_rn_(v0.x, v0.x));
    r[1] = fadd_rn_(r[1], fmul_rn_(v0.y, v0.y));
    r[2] = fadd_rn_(r[2], fmul_rn_(v0.z, v0.z));
    r[3] = fadd_rn_(r[3], fmul_rn_(v0.w, v0.w));
    r[4] = fadd_rn_(r[4], fmul_rn_(v1.x, v1.x));
    r[5] = fadd_rn_(r[5], fmul_rn_(v1.y, v1.y));
    r[6] = fadd_rn_(r[6], fmul_rn_(v1.z, v1.z));
    r[7] = fadd_rn_(r[7], fmul_rn_(v1.w, v1.w));
  }
  return fadd_rn_(fadd_rn_(fadd_rn_(r[0], r[1]), fadd_rn_(r[2], r[3])),
                  fadd_rn_(fadd_rn_(r[4], r[5]), fadd_rn_(r[6], r[7])));
}

// K_prep (16 blocks x 64 codes): cbT transpose, exact cc chain, fp16 hi/lo pack
// into 32-code chunks [hi 32x144 | lo 32x144].
__global__ __launch_bounds__(256) void k_prep(const float* __restrict__ cb,
                                              float* __restrict__ cbT,
                                              float* __restrict__ cc,
                                              _Float16* __restrict__ Bp) {
  __shared__ float tile[64 * 129];  // +1 pad: conflict-free transpose
  int t = threadIdx.x;
  int c0 = blockIdx.x * 64;
#pragma unroll
  for (int it = 0; it < 32; ++it) {
    int f = it * 256 + t;
    int c = f >> 7, d = f & 127;
    tile[c * 129 + d] = cb[(size_t)(c0 + c) * DIM + d];
  }
  __syncthreads();
#pragma unroll
  for (int it = 0; it < 32; ++it) {
    int f = it * 256 + t;
    int d = f >> 6, c = f & 63;
    cbT[(size_t)d * KC + c0 + c] = tile[c * 129 + d];
  }
  if (t < 64) {
    const float* s = &tile[t * 129];
    float r[8];
#pragma unroll
    for (int j = 0; j < 8; ++j) r[j] = fmul_rn_(s[j], s[j]);
    for (int i = 1; i < 16; ++i) {
#pragma unroll
      for (int j = 0; j < 8; ++j)
        r[j] = fadd_rn_(r[j], fmul_rn_(s[i * 8 + j], s[i * 8 + j]));
    }
    cc[c0 + t] = fadd_rn_(fadd_rn_(fadd_rn_(r[0], r[1]), fadd_rn_(r[2], r[3])),
                          fadd_rn_(fadd_rn_(r[4], r[5]), fadd_rn_(r[6], r[7])));
  }
#pragma unroll
  for (int it = 0; it < 32; ++it) {
    int f = it * 256 + t;
    int c = f >> 7, k = f & 127;       // c: 0..63 local code
    int gc = c0 + c;
    int chunk = gc >> 5, cr = gc & 31;
    float c5 = tile[c * 129 + k] * 512.0f;  // exact pow2 scale
    _Float16 h = (_Float16)c5;
    _Float16 l = (_Float16)(c5 - (float)h);
    size_t base = (size_t)chunk * CH32;
    Bp[base + cr * BSTR + k] = h;
    Bp[base + BLO + cr * BSTR + k] = l;
  }
}

// Async global->LDS stage of one 18432 B chunk: 18 wave-segments of 1 KiB
// (64 lanes x 16 B). Waves 0-3 take segs w+4*il; segs 16,17 go to waves 0,1.
// Zero destination VGPRs -> no liveness across MFMA -> no spill (R5/R7 lesson).
__device__ __forceinline__ void stage_chunk(const _Float16* Bp, _Float16* SB,
                                            int cn, int lane, int w) {
  const char* g = (const char*)Bp + (size_t)cn * CHB;
  char* l = (char*)SB + (size_t)(cn & 1) * CHB;
  int off = lane * 16;
#pragma unroll
  for (int il = 0; il < 5; ++il) {
    int s = il * 4 + w;
    if (s < 18) {
      __builtin_amdgcn_global_load_lds(
          (const __attribute__((address_space(1))) void*)(g + s * 1024 + off),
          (__attribute__((address_space(3))) void*)(l + s * 1024 + off),
          16, 0, 0);
    }
  }
}

// K_main: 64 rows/block, 256 thr (4 waves x 16 rows). fp16-split MFMA distance
// GEMM; B ping-pong staged via global_load_lds (loads for c+1 in flight during
// MFMA of c; one barrier per chunk drains them) + margin argmin + inline exact
// recheck + fused epilogue.
__global__ __launch_bounds__(256, 4) void k_main(const float* __restrict__ inp,
                                                 const float* __restrict__ cb,
                                                 const float* __restrict__ cbT,
                                                 const _Float16* __restrict__ Bp,
                                                 const float* __restrict__ cc,
                                                 float* __restrict__ out_qst,
                                                 float* __restrict__ out_enc,
                                                 int* __restrict__ cnt,
                                                 float* __restrict__ lsum) {
  __shared__ __align__(16) _Float16 SB[2 * CH32];  // 36864 B
  __shared__ float xxs[64];
  __shared__ int bk[64];
  __shared__ int fl_rows[64];
  __shared__ int fl_cnt;
  __shared__ float xs[128];
  __shared__ float redd[4];
  __shared__ int redi[4];
  __shared__ float redf[4];

  int t = threadIdx.x;
  int lane = t & 63, w = t >> 6;
  int q = lane >> 4, col = lane & 15;
  int row0 = blockIdx.x * 64;
  if (t == 0) fl_cnt = 0;

  // ---- stage A as fp16 hi/lo split (occupies BOTH B buffers temporarily) ----
  {
    int r = t & 63, seg = t >> 6;
    const float* src = inp + (size_t)(row0 + r) * DIM + seg * 32;
#pragma unroll
    for (int i = 0; i < 8; ++i) {
      float4 v = *(const float4*)(src + i * 4);
      _Float16 h0 = (_Float16)v.x, h1 = (_Float16)v.y, h2 = (_Float16)v.z, h3 = (_Float16)v.w;
      half4_t hv = {h0, h1, h2, h3};
      half4_t lv = {(_Float16)(v.x - (float)h0), (_Float16)(v.y - (float)h1),
                    (_Float16)(v.z - (float)h2), (_Float16)(v.w - (float)h3)};
      int k = seg * 32 + i * 4;
      *(half4_t*)&SB[r * BSTR + k] = hv;
      *(half4_t*)&SB[ALO + r * BSTR + k] = lv;
    }
  }
  if (t < 64) xxs[t] = rowsq128((const float4*)(inp + (size_t)(row0 + t) * DIM));
  __syncthreads();

  // ---- A frags -> registers ----
  int arow = w * 16 + col;
  half8_t ah[4], al[4];
#pragma unroll
  for (int ks = 0; ks < 4; ++ks) {
    ah[ks] = *(const half8_t*)&SB[arow * BSTR + ks * 32 + q * 8];
    al[ks] = *(const half8_t*)&SB[ALO + arow * BSTR + ks * 32 + q * 8];
  }
  float xr[4];
#pragma unroll
  for (int r = 0; r < 4; ++r) xr[r] = xxs[w * 16 + q * 4 + r];

  float b1[4], b2[4];
  int i1[4];
#pragma unroll
  for (int r = 0; r < 4; ++r) { b1[r] = 3.4e38f; b2[r] = 3.4e38f; i1[r] = 0; }

  __syncthreads();  // all waves done reading the A image from SB

  // chunk 0 -> buf0 (async DMA), drained by the next barrier
  stage_chunk(Bp, SB, 0, lane, w);
  __syncthreads();

  for (int c = 0; c < NCH; ++c) {
    const _Float16* cur = &SB[(c & 1) * CH32];

    // issue DMA for chunk c+1 into the other buffer (in flight across MFMA)
    if (c < NCH - 1) stage_chunk(Bp, SB, c + 1, lane, w);

    float cck[2];
#pragma unroll
    for (int ct = 0; ct < 2; ++ct) cck[ct] = cc[c * 32 + ct * 16 + col];

    floatx4 acc[2];
#pragma unroll
    for (int ct = 0; ct < 2; ++ct) acc[ct] = (floatx4){0.f, 0.f, 0.f, 0.f};

#pragma unroll
    for (int ks = 0; ks < 4; ++ks) {
#pragma unroll
      for (int ct = 0; ct < 2; ++ct) {
        int brow = ct * 16 + col;
        half8_t bh = *(const half8_t*)&cur[brow * BSTR + ks * 32 + q * 8];
        half8_t bl = *(const half8_t*)&cur[BLO + brow * BSTR + ks * 32 + q * 8];
        acc[ct] = __builtin_amdgcn_mfma_f32_16x16x32_f16(ah[ks], bh, acc[ct], 0, 0, 0);
        acc[ct] = __builtin_amdgcn_mfma_f32_16x16x32_f16(ah[ks], bl, acc[ct], 0, 0, 0);
        acc[ct] = __builtin_amdgcn_mfma_f32_16x16x32_f16(al[ks], bh, acc[ct], 0, 0, 0);
      }
    }

#pragma unroll
    for (int ct = 0; ct < 2; ++ct) {
#pragma unroll
      for (int r = 0; r < 4; ++r) {
        float m2 = fmul_rn_(acc[ct][r], 0.00390625f);  // fl(2*matmul), exact unscale
        float dist = fsub_rn_(fadd_rn_(xr[r], cck[ct]), m2);
        int kidx = c * 32 + ct * 16 + col;
        bool lt = dist < b1[r];
        b2[r] = lt ? b1[r] : fminf(b2[r], dist);
        i1[r] = lt ? kidx : i1[r];
        b1[r] = lt ? dist : b1[r];
      }
    }

    __syncthreads();  // drains DMA (vmcnt) -> buf[(c+1)&1] published; protects reuse
  }

  // top-2 reduce across the 16 col-lanes; tie -> lower index
#pragma unroll
  for (int r = 0; r < 4; ++r) {
    float v1 = b1[r], v2 = b2[r];
    int ii = i1[r];
    for (int off = 1; off < 16; off <<= 1) {
      float ov1 = __shfl_xor(v1, off);
      float ov2 = __shfl_xor(v2, off);
      int oi = __shfl_xor(ii, off);
      float nb1 = fminf(v1, ov1);
      float nb2 = fminf(fmaxf(v1, ov1), fminf(v2, ov2));
      ii = (ov1 < v1) ? oi : ((ov1 > v1) ? ii : min(ii, oi));
      v1 = nb1; v2 = nb2;
    }
    b1[r] = v1; b2[r] = v2; i1[r] = ii;
  }

  if (col == 0) {
#pragma unroll
    for (int r = 0; r < 4; ++r) {
      int lrow = w * 16 + q * 4 + r;
      bk[lrow] = i1[r];
      float u = (b1[r] >= 256.f) ? 9.4e-5f : 4.7e-5f;  // 3-ulp tiered margin
      if (b2[r] - b1[r] < u) {
        int p = atomicAdd(&fl_cnt, 1);
        fl_rows[p] = lrow;
      }
    }
  }
  __syncthreads();

  // ---- inline exact fp32 recheck of flagged rows (rare) ----
  int nf = fl_cnt;
  for (int f = 0; f < nf; ++f) {
    int row = fl_rows[f];
    if (t < 128) xs[t] = inp[(size_t)(row0 + row) * DIM + t];
    __syncthreads();
    float xxr = xxs[row];
    int c0 = t * 4;
    float a0 = 0.f, a1 = 0.f, a2 = 0.f, a3 = 0.f;
    for (int d = 0; d < 128; ++d) {
      float xd = xs[d];
      float4 cv = *(const float4*)&cbT[(size_t)d * KC + c0];
      a0 = __builtin_fmaf(xd, cv.x, a0);
      a1 = __builtin_fmaf(xd, cv.y, a1);
      a2 = __builtin_fmaf(xd, cv.z, a2);
      a3 = __builtin_fmaf(xd, cv.w, a3);
    }
    float aa[4] = {a0, a1, a2, a3};
    float bb = 3.4e38f;
    int bi = 0;
#pragma unroll
    for (int j = 0; j < 4; ++j) {
      float dist = fsub_rn_(fadd_rn_(xxr, cc[c0 + j]), fmul_rn_(2.0f, aa[j]));
      if (dist < bb) { bb = dist; bi = c0 + j; }
    }
    for (int off = 1; off < 64; off <<= 1) {
      float ov = __shfl_xor(bb, off);
      int oi = __shfl_xor(bi, off);
      if (ov < bb || (ov == bb && oi < bi)) { bb = ov; bi = oi; }
    }
    if (lane == 0) { redd[w] = bb; redi[w] = bi; }
    __syncthreads();
    if (t == 0) {
      float vb = redd[0];
      int ib = redi[0];
#pragma unroll
      for (int ww = 1; ww < 4; ++ww) {
        if (redd[ww] < vb || (redd[ww] == vb && redi[ww] < ib)) { vb = redd[ww]; ib = redi[ww]; }
      }
      bk[row] = ib;
    }
    __syncthreads();
  }

  // ---- epilogue (R1-proven write patterns) ----
  if (t < 64) atomicAdd(&cnt[bk[t]], 1);

  float ls = 0.f;
#pragma unroll 4
  for (int it = 0; it < 32; ++it) {
    int f = it * 256 + t;  // 64 rows x 128 d, linear
    int row = f >> 7, d = f & 127;
    size_t gro = (size_t)(row0 + row) * DIM + d;
    float x = inp[gro];
    float qv = cb[(size_t)bk[row] * DIM + d];
    float qe = fsub_rn_(qv, x);
    out_qst[gro] = fadd_rn_(x, qe);  // == np: inputs + (quantized - inputs)
    ls = __builtin_fmaf(qe, qe, ls);
  }

  for (int it = 0; it < 128; ++it) {
    int f2 = it * 256 + t;  // 64 rows x 512 f32x2
    int row = f2 >> 9, c2 = f2 & 511;
    int kk = bk[row];
    f32x2 v;
    v.x = (kk == 2 * c2) ? 1.0f : 0.0f;
    v.y = (kk == 2 * c2 + 1) ? 1.0f : 0.0f;
    *(f32x2*)&out_enc[(size_t)(row0 + row) * KC + 2 * c2] = v;
  }

  for (int off = 32; off; off >>= 1) ls += __shfl_down(ls, off);
  if (lane == 0) redf[w] = ls;
  __syncthreads();
  if (t == 0) atomicAdd(lsum, redf[0] + redf[1] + redf[2] + redf[3]);
}

// K_scalars: loss + perplexity
__global__ __launch_bounds__(1024) void k_scalars(const int* __restrict__ cnt,
                                                  const float* __restrict__ lsum,
                                                  float* __restrict__ out) {
  int t = threadIdx.x;
  float p = (float)cnt[t] * (1.0f / 65536.0f);
  float term = fmul_rn_(p, logf(fadd_rn_(p, 1e-10f)));
  for (int off = 32; off; off >>= 1) term += __shfl_down(term, off);
  __shared__ float red[16];
  if ((t & 63) == 0) red[t >> 6] = term;
  __syncthreads();
  if (t == 0) {
    float s = 0.f;
#pragma unroll
    for (int w = 0; w < 16; ++w) s += red[w];
    out[PPL_OFF] = expf(-s);
    float e = *lsum * (1.0f / 8388608.0f);
    out[0] = fadd_rn_(e, fmul_rn_(0.25f, e));  // q_latent + 0.25*e_latent (equal)
  }
}

extern "C" void kernel_launch(void* const* d_in, const int* in_sizes, int n_in,
                              void* d_out, int out_size, void* d_ws, size_t ws_size,
                              hipStream_t stream) {
  const float* inp = (const float*)d_in[0];
  const float* cb = (const float*)d_in[1];
  float* out = (float*)d_out;

  _Float16* Bp = (_Float16*)d_ws;          // 32*9216 halfs = 589824 B
  float* cbT = (float*)(Bp + 32 * CH32);   // 131072 f32
  float* cc = cbT + DIM * KC;              // 1024 f32
  int* cnt = (int*)(cc + KC);              // 1024 i32
  float* lsum = (float*)(cnt + KC);        // 1 f32

  (void)hipMemsetAsync(cnt, 0, (KC + 1) * sizeof(int), stream);
  k_prep<<<KC / 64, 256, 0, stream>>>(cb, cbT, cc, Bp);
  k_main<<<NROWS / 64, 256, 0, stream>>>(inp, cb, cbT, Bp, cc,
                                         out + QST_OFF, out + ENC_OFF, cnt, lsum);
  k_scalars<<<1, 1024, 0, stream>>>(cnt, lsum, out);
}